// Round 1
// baseline (1053.105 us; speedup 1.0000x reference)
//
#include <hip/hip_runtime.h>
#include <hip/hip_bf16.h>
#include <cstdint>

#define DM   1024
#define DFF  2048
#define NH   16
#define DK   64
#define BBATCH 512
#define LSEQ 60
#define M_TOK (BBATCH*LSEQ)   // 30720
#define NQKV (3*DM)           // 3072

typedef __attribute__((ext_vector_type(8))) short bf16x8;
typedef __attribute__((ext_vector_type(4))) float f32x4;
typedef __attribute__((ext_vector_type(8))) unsigned short u16x8;
typedef __attribute__((ext_vector_type(4))) unsigned short u16x4;

__device__ __forceinline__ unsigned short f2bf(float f) {
  union { float f; unsigned u; } x; x.f = f;
  unsigned r = x.u + 0x7fffu + ((x.u >> 16) & 1u);   // RNE
  return (unsigned short)(r >> 16);
}

__device__ __forceinline__ void gload_lds16(const void* g, void* l) {
  __builtin_amdgcn_global_load_lds(
      (const __attribute__((address_space(1))) unsigned int*)g,
      (__attribute__((address_space(3))) unsigned int*)l, 16, 0, 0);
}

// C = A(bf16,[M x K] lda) @ B(bf16,[N x K] ldb)^T ; 128x128 tile, 4 waves, BK=32.
// MODE 0: C bf16    MODE 1: C fp32 = acc + Res[row*ldc+col]   MODE 2: C bf16 = relu(acc)
template<int MODE>
__global__ __launch_bounds__(256)
void gemm_bt(const unsigned short* __restrict__ A, int lda,
             const unsigned short* __restrict__ B, int ldb,
             void* __restrict__ Cv, int ldc,
             const float* __restrict__ Res, int K) {
  __shared__ unsigned short As[128*32];
  __shared__ unsigned short Bs[128*32];
  const int t  = threadIdx.x;
  const int l  = t & 63;
  const int w  = t >> 6;
  const int lo = l & 15, hi = l >> 4;
  const int wr = w >> 1, wc = w & 1;
  const long row0 = (long)blockIdx.y * 128;
  const long col0 = (long)blockIdx.x * 128;

  f32x4 zero4 = {0.f,0.f,0.f,0.f};
  f32x4 acc[4][4];
#pragma unroll
  for (int m=0;m<4;++m)
#pragma unroll
    for (int n=0;n<4;++n) acc[m][n] = zero4;

  const int nkt = K >> 5;
  for (int kt = 0; kt < nkt; ++kt) {
    const int k0 = kt*32;
#pragma unroll
    for (int i=0;i<2;++i) {
      int idx = i*256 + t;
      int ar = idx >> 2, ac = (idx & 3) * 8;
      gload_lds16(A + (size_t)(row0+ar)*lda + k0 + ac, &As[idx*8]);
      gload_lds16(B + (size_t)(col0+ar)*ldb + k0 + ac, &Bs[idx*8]);
    }
    __syncthreads();
    bf16x8 af[4], bfr[4];
#pragma unroll
    for (int m=0;m<4;++m) af[m]  = *(const bf16x8*)&As[(wr*64 + m*16 + lo)*32 + hi*8];
#pragma unroll
    for (int n=0;n<4;++n) bfr[n] = *(const bf16x8*)&Bs[(wc*64 + n*16 + lo)*32 + hi*8];
#pragma unroll
    for (int m=0;m<4;++m)
#pragma unroll
      for (int n=0;n<4;++n)
        acc[m][n] = __builtin_amdgcn_mfma_f32_16x16x32_bf16(af[m], bfr[n], acc[m][n], 0,0,0);
    __syncthreads();
  }

#pragma unroll
  for (int m=0;m<4;++m) {
#pragma unroll
    for (int r=0;r<4;++r) {
      long row = row0 + wr*64 + m*16 + hi*4 + r;
      size_t base = (size_t)row * ldc;
#pragma unroll
      for (int n=0;n<4;++n) {
        long col = col0 + wc*64 + n*16 + lo;
        float v = acc[m][n][r];
        if (MODE == 0) {
          ((unsigned short*)Cv)[base + col] = f2bf(v);
        } else if (MODE == 1) {
          ((float*)Cv)[base + col] = v + Res[base + col];
        } else {
          ((unsigned short*)Cv)[base + col] = f2bf(v > 0.f ? v : 0.f);
        }
      }
    }
  }
}

// One block per (b,h). qkv: [M_TOK][3072] bf16 (Q|K|V). ctx written in-place over Q cols.
__global__ __launch_bounds__(256)
void attn_kernel(unsigned short* qkv, const float* __restrict__ att_sig,
                 float* __restrict__ loss_part) {
  __shared__ unsigned short qs[64*64], ks[64*64], vts[64*64], as2[64*64];
  __shared__ float red[4];
  const int bid = blockIdx.x;
  const int b = bid >> 4, h = bid & 15;
  const int t = threadIdx.x;
  const int l = t & 63, w = t >> 6, lo = l & 15, hi = l >> 4;

  // load q,k rows + v transposed; pad rows/cols 60..63 with zeros
#pragma unroll
  for (int p=0;p<2;++p) {
    int row = p*32 + (t>>3);
    int d0  = (t&7)*8;
    u16x8 zq = {0,0,0,0,0,0,0,0}; u16x8 zk = zq; u16x8 zv = zq;
    if (row < LSEQ) {
      size_t g = (size_t)(b*LSEQ + row)*NQKV + h*DK + d0;
      zq = *(const u16x8*)(qkv + g);
      zk = *(const u16x8*)(qkv + g + DM);
      zv = *(const u16x8*)(qkv + g + 2*DM);
    }
    *(u16x8*)&qs[row*64 + d0] = zq;
    *(u16x8*)&ks[row*64 + d0] = zk;
#pragma unroll
    for (int j=0;j<8;++j) vts[(d0+j)*64 + row] = zv[j];
  }
  __syncthreads();

  // S = q @ k^T ; wave w owns rows 16w..16w+15
  f32x4 zero4 = {0.f,0.f,0.f,0.f};
  f32x4 sacc[4];
#pragma unroll
  for (int ct=0;ct<4;++ct) sacc[ct] = zero4;
  bf16x8 aq[2];
  aq[0] = *(const bf16x8*)&qs[(w*16+lo)*64 + hi*8];
  aq[1] = *(const bf16x8*)&qs[(w*16+lo)*64 + 32 + hi*8];
#pragma unroll
  for (int ct=0;ct<4;++ct)
#pragma unroll
    for (int kk=0;kk<2;++kk) {
      bf16x8 bk = *(const bf16x8*)&ks[(ct*16+lo)*64 + kk*32 + hi*8];
      sacc[ct] = __builtin_amdgcn_mfma_f32_16x16x32_bf16(aq[kk], bk, sacc[ct], 0,0,0);
    }

  // softmax over cols (mask col>=60), loss, store attn bf16 to as2
  float lloss = 0.f;
  const float SC = 0.125f;   // 1/sqrt(64)
#pragma unroll
  for (int r=0;r<4;++r) {
    int row = w*16 + hi*4 + r;
    float v0 = sacc[0][r]*SC, v1 = sacc[1][r]*SC, v2 = sacc[2][r]*SC;
    float v3 = (lo < 12) ? sacc[3][r]*SC : -__builtin_inff();
    float mx = fmaxf(fmaxf(v0,v1), fmaxf(v2,v3));
#pragma unroll
    for (int d=1; d<16; d<<=1) mx = fmaxf(mx, __shfl_xor(mx, d, 64));
    float p0=__expf(v0-mx), p1=__expf(v1-mx), p2=__expf(v2-mx), p3=__expf(v3-mx);
    float sm = p0+p1+p2+p3;
#pragma unroll
    for (int d=1; d<16; d<<=1) sm += __shfl_xor(sm, d, 64);
    float inv = 1.0f / sm;
    float a0=p0*inv, a1=p1*inv, a2=p2*inv, a3=p3*inv;
    if (row < LSEQ) {
      float df;
      df = a0 - att_sig[row*LSEQ + lo];       lloss += df*df;
      df = a1 - att_sig[row*LSEQ + 16 + lo];  lloss += df*df;
      df = a2 - att_sig[row*LSEQ + 32 + lo];  lloss += df*df;
      if (lo < 12) { df = a3 - att_sig[row*LSEQ + 48 + lo]; lloss += df*df; }
    }
    as2[row*64 + lo]      = f2bf(a0);
    as2[row*64 + 16 + lo] = f2bf(a1);
    as2[row*64 + 32 + lo] = f2bf(a2);
    as2[row*64 + 48 + lo] = f2bf(a3);   // 0 for lo>=12
  }
  __syncthreads();

  // ctx = attn @ v
  f32x4 cacc[4];
#pragma unroll
  for (int n=0;n<4;++n) cacc[n] = zero4;
  bf16x8 ap[2];
  ap[0] = *(const bf16x8*)&as2[(w*16+lo)*64 + hi*8];
  ap[1] = *(const bf16x8*)&as2[(w*16+lo)*64 + 32 + hi*8];
#pragma unroll
  for (int n=0;n<4;++n)
#pragma unroll
    for (int kk=0;kk<2;++kk) {
      bf16x8 bv = *(const bf16x8*)&vts[(n*16+lo)*64 + kk*32 + hi*8];
      cacc[n] = __builtin_amdgcn_mfma_f32_16x16x32_bf16(ap[kk], bv, cacc[n], 0,0,0);
    }
#pragma unroll
  for (int r=0;r<4;++r) {
    int row = w*16 + hi*4 + r;
    if (row < LSEQ) {
      size_t g = (size_t)(b*LSEQ + row)*NQKV + h*DK;
#pragma unroll
      for (int n=0;n<4;++n)
        qkv[g + n*16 + lo] = f2bf(cacc[n][r]);
    }
  }

  // block loss partial (deterministic two-stage: per-block then fixed-order reduce)
#pragma unroll
  for (int d=1; d<64; d<<=1) lloss += __shfl_xor(lloss, d, 64);
  if (l == 0) red[w] = lloss;
  __syncthreads();
  if (t == 0) loss_part[bid] = red[0]+red[1]+red[2]+red[3];
}

__global__ __launch_bounds__(256)
void reduce_loss(const float* __restrict__ part, float* __restrict__ out) {
  __shared__ float red[4];
  float s = 0.f;
  for (int i = threadIdx.x; i < BBATCH*NH; i += 256) s += part[i];
#pragma unroll
  for (int d=1; d<64; d<<=1) s += __shfl_xor(s, d, 64);
  if ((threadIdx.x & 63) == 0) red[threadIdx.x >> 6] = s;
  __syncthreads();
  if (threadIdx.x == 0) out[0] = red[0]+red[1]+red[2]+red[3];
}

// Row LayerNorm in place on io (fp32, row = blockIdx.x), optional bf16 copy to ob.
template<int WB>
__global__ __launch_bounds__(256)
void ln_kernel(float* __restrict__ io, const float* __restrict__ gw,
               const float* __restrict__ gb, unsigned short* __restrict__ ob) {
  __shared__ float red[4];
  const int t = threadIdx.x;
  const size_t base = (size_t)blockIdx.x * DM;
  float4 v = ((const float4*)(io + base))[t];
  float s = v.x+v.y+v.z+v.w;
#pragma unroll
  for (int d=1; d<64; d<<=1) s += __shfl_xor(s, d, 64);
  if ((t&63)==0) red[t>>6] = s;
  __syncthreads();
  float mean = (red[0]+red[1]+red[2]+red[3]) * (1.f/DM);
  __syncthreads();
  float dx0=v.x-mean, dx1=v.y-mean, dx2=v.z-mean, dx3=v.w-mean;
  float q = dx0*dx0+dx1*dx1+dx2*dx2+dx3*dx3;
#pragma unroll
  for (int d=1; d<64; d<<=1) q += __shfl_xor(q, d, 64);
  if ((t&63)==0) red[t>>6] = q;
  __syncthreads();
  float var = (red[0]+red[1]+red[2]+red[3]) * (1.f/DM);
  float inv = rsqrtf(var + 1e-5f);
  float4 wv = ((const float4*)gw)[t];
  float4 bv = ((const float4*)gb)[t];
  float4 o;
  o.x = dx0*inv*wv.x + bv.x;
  o.y = dx1*inv*wv.y + bv.y;
  o.z = dx2*inv*wv.z + bv.z;
  o.w = dx3*inv*wv.w + bv.w;
  ((float4*)(io + base))[t] = o;
  if (WB) {
    u16x4 ub; ub[0]=f2bf(o.x); ub[1]=f2bf(o.y); ub[2]=f2bf(o.z); ub[3]=f2bf(o.w);
    *(u16x4*)(ob + base + t*4) = ub;
  }
}

__global__ __launch_bounds__(256)
void cast_bf16(const float* __restrict__ in, unsigned short* __restrict__ out, int n4) {
  int i = blockIdx.x*256 + threadIdx.x;
  int stride = gridDim.x*256;
  for (; i < n4; i += stride) {
    float4 v = ((const float4*)in)[i];
    u16x4 u; u[0]=f2bf(v.x); u[1]=f2bf(v.y); u[2]=f2bf(v.z); u[3]=f2bf(v.w);
    ((u16x4*)out)[i] = u;
  }
}

extern "C" void kernel_launch(void* const* d_in, const int* in_sizes, int n_in,
                              void* d_out, int out_size, void* d_ws, size_t ws_size,
                              hipStream_t stream) {
  const float* x      = (const float*)d_in[0];
  const float* attsig = (const float*)d_in[1];
  const float* wq     = (const float*)d_in[2];
  const float* wk     = (const float*)d_in[3];
  const float* wv     = (const float*)d_in[4];
  const float* wo     = (const float*)d_in[5];
  const float* ln1w   = (const float*)d_in[6];
  const float* ln1b   = (const float*)d_in[7];
  const float* w1     = (const float*)d_in[8];
  const float* w2     = (const float*)d_in[9];
  const float* ln2w   = (const float*)d_in[10];
  const float* ln2b   = (const float*)d_in[11];

  char* ws = (char*)d_ws;
  unsigned short* xb    = (unsigned short*)(ws);              // 30720x1024 bf16 (later reused: LN1 bf16 out)
  unsigned short* wqkvb = (unsigned short*)(ws + 62914560ull);// 3072x1024
  unsigned short* wob   = (unsigned short*)(ws + 69206016ull);// 1024x1024
  unsigned short* w1b   = (unsigned short*)(ws + 71303168ull);// 2048x1024
  unsigned short* w2b   = (unsigned short*)(ws + 75497472ull);// 1024x2048
  unsigned short* qkv   = (unsigned short*)(ws + 79691776ull);// 30720x3072 (ctx overwrites Q cols)
  unsigned short* h1    = (unsigned short*)(ws + 268435456ull);// 30720x2048
  float*          lpart = (float*)(ws + 394264576ull);        // 8192

  float* outf = (float*)d_out;                 // 30720x1024 fp32 scratch & final out2
  float* loss = outf + (size_t)M_TOK*DM;       // d_out[31457280]

  // casts to bf16
  cast_bf16<<<2048,256,0,stream>>>(x,  xb,               M_TOK*DM/4);
  cast_bf16<<<256, 256,0,stream>>>(wq, wqkvb,            DM*DM/4);
  cast_bf16<<<256, 256,0,stream>>>(wk, wqkvb + DM*DM,    DM*DM/4);
  cast_bf16<<<256, 256,0,stream>>>(wv, wqkvb + 2*DM*DM,  DM*DM/4);
  cast_bf16<<<256, 256,0,stream>>>(wo, wob,              DM*DM/4);
  cast_bf16<<<512, 256,0,stream>>>(w1, w1b,              DM*DFF/4);
  cast_bf16<<<512, 256,0,stream>>>(w2, w2b,              DM*DFF/4);

  // fused QKV projection: [30720,1024] @ [3072,1024]^T -> bf16 [30720,3072]
  gemm_bt<0><<<dim3(NQKV/128, M_TOK/128), 256, 0, stream>>>(xb, DM, wqkvb, DM, qkv, NQKV, nullptr, DM);

  // attention + loss partials
  attn_kernel<<<BBATCH*NH, 256, 0, stream>>>(qkv, attsig, lpart);
  reduce_loss<<<1,256,0,stream>>>(lpart, loss);

  // out_pre = ctx @ wo^T + x  (fp32 into d_out)
  gemm_bt<1><<<dim3(DM/128, M_TOK/128), 256, 0, stream>>>(qkv, NQKV, wob, DM, outf, DM, x, DM);
  // LN1 in place, bf16 copy into xb
  ln_kernel<1><<<M_TOK,256,0,stream>>>(outf, ln1w, ln1b, xb);
  // h1 = relu(out @ w1^T) bf16
  gemm_bt<2><<<dim3(DFF/128, M_TOK/128), 256, 0, stream>>>(xb, DM, w1b, DM, h1, DFF, nullptr, DM);
  // ff_pre = h1 @ w2^T + out (fp32, in d_out)
  gemm_bt<1><<<dim3(DM/128, M_TOK/128), 256, 0, stream>>>(h1, DFF, w2b, DFF, outf, DM, outf, DFF);
  // LN2 in place -> final out2
  ln_kernel<0><<<M_TOK,256,0,stream>>>(outf, ln2w, ln2b, nullptr);
}

// Round 2
// 800.777 us; speedup vs baseline: 1.3151x; 1.3151x over previous
//
#include <hip/hip_runtime.h>
#include <hip/hip_bf16.h>
#include <cstdint>

#define DM   1024
#define DFF  2048
#define NH   16
#define DK   64
#define BBATCH 512
#define LSEQ 60
#define M_TOK (BBATCH*LSEQ)   // 30720
#define NQKV (3*DM)           // 3072
#define NTM  120              // M_TOK / 256

typedef __attribute__((ext_vector_type(8))) short bf16x8;
typedef __attribute__((ext_vector_type(4))) float f32x4;
typedef __attribute__((ext_vector_type(8))) unsigned short u16x8;
typedef __attribute__((ext_vector_type(4))) unsigned short u16x4;

__device__ __forceinline__ unsigned short f2bf(float f) {
  union { float f; unsigned u; } x; x.f = f;
  unsigned r = x.u + 0x7fffu + ((x.u >> 16) & 1u);   // RNE
  return (unsigned short)(r >> 16);
}

__device__ __forceinline__ void gload_lds16(const void* g, void* l) {
  __builtin_amdgcn_global_load_lds(
      (const __attribute__((address_space(1))) unsigned int*)g,
      (__attribute__((address_space(3))) unsigned int*)l, 16, 0, 0);
}

// Stage one 128x64 bf16 half-tile (16 KB) into LDS, linear dest, inverse-
// swizzled global source (swizzle: byte ^= ((row&7)<<4) within each row).
__device__ __forceinline__ void stage_half(
    const unsigned short* __restrict__ G, int ld, long rowbase, int k0,
    unsigned short* sbase, int w, int l) {
#pragma unroll
  for (int j = 0; j < 2; ++j) {
    const int sig = (w*2 + j)*1024 + l*16;           // byte offset in half
    const int row = sig >> 7;                        // 0..127
    const int cb  = (sig & 127) ^ ((row & 7) << 4);  // inverse swizzle on src
    gload_lds16(G + (size_t)(rowbase + row)*ld + k0 + (cb >> 1),
                (char*)sbase + (w*2 + j)*1024);
  }
}

__device__ __forceinline__ bf16x8 lds_frag(const unsigned short* base, int row,
                                           int cb, int swz) {
  return *(const bf16x8*)((const char*)base + row*128 + (cb ^ swz));
}

// C = A(bf16,[M x K] lda) @ B(bf16,[N x K] ldb)^T ; 256x256 tile, BK=64,
// 8 waves (2Mx4N), double-buffered LDS, 4-phase-per-K-tile counted-vmcnt
// schedule (T2 swizzle + T3/T4 + T5). M fixed = 30720 (NTM tiles).
// MODE 0: C bf16    MODE 1: C fp32 = acc + Res    MODE 2: C bf16 = relu(acc)
template<int MODE>
__global__ __launch_bounds__(512, 2)
void gemm256(const unsigned short* __restrict__ A, int lda,
             const unsigned short* __restrict__ B, int ldb,
             void* __restrict__ Cv, int ldc,
             const float* __restrict__ Res, int K) {
  __shared__ unsigned short sm[65536];   // A0|A1|B0|B1, 32 KB each

  const int t  = threadIdx.x;
  const int l  = t & 63, w = t >> 6;
  const int lo = l & 15, hi = l >> 4;
  const int wr = w >> 2, wc = w & 3;
  const int swz = (lo & 7) << 4;

  // T1: bijective XCD swizzle (grid always % 8 == 0 here), then 4-wide
  // n-groups with m sweeping inside (A-tile shared by 4 consecutive wgids).
  const int nwg = (int)gridDim.x;
  int wg = (int)blockIdx.x;
  wg = (wg & 7) * (nwg >> 3) + (wg >> 3);
  const int ng  = wg / (NTM*4);
  const int rem = wg - ng*(NTM*4);
  const long row0 = (long)(rem >> 2) * 256;
  const long col0 = (long)(ng*4 + (rem & 3)) * 256;

  f32x4 acc[8][4];
#pragma unroll
  for (int m=0;m<8;++m)
#pragma unroll
    for (int n=0;n<4;++n) acc[m][n] = (f32x4){0.f,0.f,0.f,0.f};

  const int nkt = K >> 6;

  // prologue: tile0 A+B, tile1 A
  stage_half(A, lda, row0,       0, sm,                 w, l);
  stage_half(A, lda, row0+128,   0, sm + 8192,          w, l);
  stage_half(B, ldb, col0,       0, sm + 32768,         w, l);
  stage_half(B, ldb, col0+128,   0, sm + 32768 + 8192,  w, l);
  stage_half(A, lda, row0,      64, sm + 16384,         w, l);
  stage_half(A, lda, row0+128,  64, sm + 16384 + 8192,  w, l);
  asm volatile("s_waitcnt vmcnt(4)" ::: "memory");
  __builtin_amdgcn_s_barrier();

  for (int kt = 0; kt < nkt; ++kt) {
    const int cur = kt & 1, nxt = cur ^ 1;
    const unsigned short* Ac = sm + cur*16384;
    const unsigned short* Bc = sm + 32768 + cur*16384;
    unsigned short* Bn = sm + 32768 + nxt*16384;
    unsigned short* An = sm + cur*16384;          // A(kt+2) reuses cur buffer
    const int rowA = wr*128 + lo;
    const int rowB = wc*64 + lo;
    bf16x8 a0[4][2], a1[4][2], b0[2][2], b2[2][2];

    // ---- P1: ds_read a0(8)+b0(4); stage B-half0(kt+1); MFMA q(0,0) ----
#pragma unroll
    for (int m=0;m<4;++m)
#pragma unroll
      for (int ks=0;ks<2;++ks)
        a0[m][ks] = lds_frag(Ac, rowA + m*16, ks*64 + hi*16, swz);
#pragma unroll
    for (int n=0;n<2;++n)
#pragma unroll
      for (int ks=0;ks<2;++ks)
        b0[n][ks] = lds_frag(Bc, rowB + n*16, ks*64 + hi*16, swz);
    if (kt+1 < nkt) stage_half(B, ldb, col0, (kt+1)*64, Bn, w, l);
    asm volatile("s_waitcnt lgkmcnt(8)" ::: "memory");
    __builtin_amdgcn_s_barrier();
    asm volatile("s_waitcnt lgkmcnt(0)" ::: "memory");
    __builtin_amdgcn_s_setprio(1);
#pragma unroll
    for (int m=0;m<4;++m)
#pragma unroll
      for (int n=0;n<2;++n)
#pragma unroll
        for (int ks=0;ks<2;++ks)
          acc[m][n] = __builtin_amdgcn_mfma_f32_16x16x32_bf16(a0[m][ks], b0[n][ks], acc[m][n], 0,0,0);
    __builtin_amdgcn_s_setprio(0);
    __builtin_amdgcn_s_barrier();

    // ---- P2: ds_read b2(4); stage B-half1(kt+1); MFMA q(0,1) ----
#pragma unroll
    for (int n=0;n<2;++n)
#pragma unroll
      for (int ks=0;ks<2;++ks)
        b2[n][ks] = lds_frag(Bc, rowB + (n+2)*16, ks*64 + hi*16, swz);
    if (kt+1 < nkt) stage_half(B, ldb, col0+128, (kt+1)*64, Bn + 8192, w, l);
    __builtin_amdgcn_s_barrier();
    asm volatile("s_waitcnt lgkmcnt(0)" ::: "memory");
    __builtin_amdgcn_s_setprio(1);
#pragma unroll
    for (int m=0;m<4;++m)
#pragma unroll
      for (int n=0;n<2;++n)
#pragma unroll
        for (int ks=0;ks<2;++ks)
          acc[m][2+n] = __builtin_amdgcn_mfma_f32_16x16x32_bf16(a0[m][ks], b2[n][ks], acc[m][2+n], 0,0,0);
    __builtin_amdgcn_s_setprio(0);
    __builtin_amdgcn_s_barrier();

    // ---- P3: ds_read a1(8); MFMA q(1,0) ----
#pragma unroll
    for (int m=0;m<4;++m)
#pragma unroll
      for (int ks=0;ks<2;++ks)
        a1[m][ks] = lds_frag(Ac, rowA + (m+4)*16, ks*64 + hi*16, swz);
    __builtin_amdgcn_s_barrier();
    asm volatile("s_waitcnt lgkmcnt(0)" ::: "memory");
    __builtin_amdgcn_s_setprio(1);
#pragma unroll
    for (int m=0;m<4;++m)
#pragma unroll
      for (int n=0;n<2;++n)
#pragma unroll
        for (int ks=0;ks<2;++ks)
          acc[4+m][n] = __builtin_amdgcn_mfma_f32_16x16x32_bf16(a1[m][ks], b0[n][ks], acc[4+m][n], 0,0,0);
    __builtin_amdgcn_s_setprio(0);
    __builtin_amdgcn_s_barrier();

    // ---- P4: stage A halves(kt+2); counted vmcnt; MFMA q(1,1) ----
    if (kt+2 < nkt) {
      stage_half(A, lda, row0,     (kt+2)*64, An,        w, l);
      stage_half(A, lda, row0+128, (kt+2)*64, An + 8192, w, l);
      asm volatile("s_waitcnt vmcnt(4)" ::: "memory");
    } else {
      asm volatile("s_waitcnt vmcnt(0)" ::: "memory");
    }
    __builtin_amdgcn_s_barrier();
    __builtin_amdgcn_s_setprio(1);
#pragma unroll
    for (int m=0;m<4;++m)
#pragma unroll
      for (int n=0;n<2;++n)
#pragma unroll
        for (int ks=0;ks<2;++ks)
          acc[4+m][2+n] = __builtin_amdgcn_mfma_f32_16x16x32_bf16(a1[m][ks], b2[n][ks], acc[4+m][2+n], 0,0,0);
    __builtin_amdgcn_s_setprio(0);
    __builtin_amdgcn_s_barrier();
  }

  // epilogue
#pragma unroll
  for (int m=0;m<8;++m) {
#pragma unroll
    for (int r=0;r<4;++r) {
      const long row = row0 + wr*128 + m*16 + hi*4 + r;
      const size_t base = (size_t)row * ldc;
#pragma unroll
      for (int n=0;n<4;++n) {
        const long col = col0 + wc*64 + n*16 + lo;
        const float v = acc[m][n][r];
        if (MODE == 0) {
          ((unsigned short*)Cv)[base + col] = f2bf(v);
        } else if (MODE == 1) {
          ((float*)Cv)[base + col] = v + Res[base + col];
        } else {
          ((unsigned short*)Cv)[base + col] = f2bf(v > 0.f ? v : 0.f);
        }
      }
    }
  }
}

// One block per (b,h). qkv: [M_TOK][3072] bf16 (Q|K|V). ctx written in-place over Q cols.
__global__ __launch_bounds__(256)
void attn_kernel(unsigned short* qkv, const float* __restrict__ att_sig,
                 float* __restrict__ loss_part) {
  __shared__ unsigned short qs[64*64], ks[64*64], vts[64*64], as2[64*64];
  __shared__ float red[4];
  const int bid = blockIdx.x;
  const int b = bid >> 4, h = bid & 15;
  const int t = threadIdx.x;
  const int l = t & 63, w = t >> 6, lo = l & 15, hi = l >> 4;

#pragma unroll
  for (int p=0;p<2;++p) {
    int row = p*32 + (t>>3);
    int d0  = (t&7)*8;
    u16x8 zq = {0,0,0,0,0,0,0,0}; u16x8 zk = zq; u16x8 zv = zq;
    if (row < LSEQ) {
      size_t g = (size_t)(b*LSEQ + row)*NQKV + h*DK + d0;
      zq = *(const u16x8*)(qkv + g);
      zk = *(const u16x8*)(qkv + g + DM);
      zv = *(const u16x8*)(qkv + g + 2*DM);
    }
    *(u16x8*)&qs[row*64 + d0] = zq;
    *(u16x8*)&ks[row*64 + d0] = zk;
#pragma unroll
    for (int j=0;j<8;++j) vts[(d0+j)*64 + row] = zv[j];
  }
  __syncthreads();

  f32x4 zero4 = {0.f,0.f,0.f,0.f};
  f32x4 sacc[4];
#pragma unroll
  for (int ct=0;ct<4;++ct) sacc[ct] = zero4;
  bf16x8 aq[2];
  aq[0] = *(const bf16x8*)&qs[(w*16+lo)*64 + hi*8];
  aq[1] = *(const bf16x8*)&qs[(w*16+lo)*64 + 32 + hi*8];
#pragma unroll
  for (int ct=0;ct<4;++ct)
#pragma unroll
    for (int kk=0;kk<2;++kk) {
      bf16x8 bk = *(const bf16x8*)&ks[(ct*16+lo)*64 + kk*32 + hi*8];
      sacc[ct] = __builtin_amdgcn_mfma_f32_16x16x32_bf16(aq[kk], bk, sacc[ct], 0,0,0);
    }

  float lloss = 0.f;
  const float SC = 0.125f;
#pragma unroll
  for (int r=0;r<4;++r) {
    int row = w*16 + hi*4 + r;
    float v0 = sacc[0][r]*SC, v1 = sacc[1][r]*SC, v2 = sacc[2][r]*SC;
    float v3 = (lo < 12) ? sacc[3][r]*SC : -__builtin_inff();
    float mx = fmaxf(fmaxf(v0,v1), fmaxf(v2,v3));
#pragma unroll
    for (int d=1; d<16; d<<=1) mx = fmaxf(mx, __shfl_xor(mx, d, 64));
    float p0=__expf(v0-mx), p1=__expf(v1-mx), p2=__expf(v2-mx), p3=__expf(v3-mx);
    float sm = p0+p1+p2+p3;
#pragma unroll
    for (int d=1; d<16; d<<=1) sm += __shfl_xor(sm, d, 64);
    float inv = 1.0f / sm;
    float a0=p0*inv, a1=p1*inv, a2=p2*inv, a3=p3*inv;
    if (row < LSEQ) {
      float df;
      df = a0 - att_sig[row*LSEQ + lo];       lloss += df*df;
      df = a1 - att_sig[row*LSEQ + 16 + lo];  lloss += df*df;
      df = a2 - att_sig[row*LSEQ + 32 + lo];  lloss += df*df;
      if (lo < 12) { df = a3 - att_sig[row*LSEQ + 48 + lo]; lloss += df*df; }
    }
    as2[row*64 + lo]      = f2bf(a0);
    as2[row*64 + 16 + lo] = f2bf(a1);
    as2[row*64 + 32 + lo] = f2bf(a2);
    as2[row*64 + 48 + lo] = f2bf(a3);
  }
  __syncthreads();

  f32x4 cacc[4];
#pragma unroll
  for (int n=0;n<4;++n) cacc[n] = zero4;
  bf16x8 ap[2];
  ap[0] = *(const bf16x8*)&as2[(w*16+lo)*64 + hi*8];
  ap[1] = *(const bf16x8*)&as2[(w*16+lo)*64 + 32 + hi*8];
#pragma unroll
  for (int n=0;n<4;++n)
#pragma unroll
    for (int kk=0;kk<2;++kk) {
      bf16x8 bv = *(const bf16x8*)&vts[(n*16+lo)*64 + kk*32 + hi*8];
      cacc[n] = __builtin_amdgcn_mfma_f32_16x16x32_bf16(ap[kk], bv, cacc[n], 0,0,0);
    }
#pragma unroll
  for (int r=0;r<4;++r) {
    int row = w*16 + hi*4 + r;
    if (row < LSEQ) {
      size_t g = (size_t)(b*LSEQ + row)*NQKV + h*DK;
#pragma unroll
      for (int n=0;n<4;++n)
        qkv[g + n*16 + lo] = f2bf(cacc[n][r]);
    }
  }

#pragma unroll
  for (int d=1; d<64; d<<=1) lloss += __shfl_xor(lloss, d, 64);
  if (l == 0) red[w] = lloss;
  __syncthreads();
  if (t == 0) loss_part[bid] = red[0]+red[1]+red[2]+red[3];
}

__global__ __launch_bounds__(256)
void reduce_loss(const float* __restrict__ part, float* __restrict__ out) {
  __shared__ float red[4];
  float s = 0.f;
  for (int i = threadIdx.x; i < BBATCH*NH; i += 256) s += part[i];
#pragma unroll
  for (int d=1; d<64; d<<=1) s += __shfl_xor(s, d, 64);
  if ((threadIdx.x & 63) == 0) red[threadIdx.x >> 6] = s;
  __syncthreads();
  if (threadIdx.x == 0) out[0] = red[0]+red[1]+red[2]+red[3];
}

template<int WB>
__global__ __launch_bounds__(256)
void ln_kernel(float* __restrict__ io, const float* __restrict__ gw,
               const float* __restrict__ gb, unsigned short* __restrict__ ob) {
  __shared__ float red[4];
  const int t = threadIdx.x;
  const size_t base = (size_t)blockIdx.x * DM;
  float4 v = ((const float4*)(io + base))[t];
  float s = v.x+v.y+v.z+v.w;
#pragma unroll
  for (int d=1; d<64; d<<=1) s += __shfl_xor(s, d, 64);
  if ((t&63)==0) red[t>>6] = s;
  __syncthreads();
  float mean = (red[0]+red[1]+red[2]+red[3]) * (1.f/DM);
  __syncthreads();
  float dx0=v.x-mean, dx1=v.y-mean, dx2=v.z-mean, dx3=v.w-mean;
  float q = dx0*dx0+dx1*dx1+dx2*dx2+dx3*dx3;
#pragma unroll
  for (int d=1; d<64; d<<=1) q += __shfl_xor(q, d, 64);
  if ((t&63)==0) red[t>>6] = q;
  __syncthreads();
  float var = (red[0]+red[1]+red[2]+red[3]) * (1.f/DM);
  float inv = rsqrtf(var + 1e-5f);
  float4 wv = ((const float4*)gw)[t];
  float4 bv = ((const float4*)gb)[t];
  float4 o;
  o.x = dx0*inv*wv.x + bv.x;
  o.y = dx1*inv*wv.y + bv.y;
  o.z = dx2*inv*wv.z + bv.z;
  o.w = dx3*inv*wv.w + bv.w;
  ((float4*)(io + base))[t] = o;
  if (WB) {
    u16x4 ub; ub[0]=f2bf(o.x); ub[1]=f2bf(o.y); ub[2]=f2bf(o.z); ub[3]=f2bf(o.w);
    *(u16x4*)(ob + base + t*4) = ub;
  }
}

__global__ __launch_bounds__(256)
void cast_bf16(const float* __restrict__ in, unsigned short* __restrict__ out, int n4) {
  int i = blockIdx.x*256 + threadIdx.x;
  int stride = gridDim.x*256;
  for (; i < n4; i += stride) {
    float4 v = ((const float4*)in)[i];
    u16x4 u; u[0]=f2bf(v.x); u[1]=f2bf(v.y); u[2]=f2bf(v.z); u[3]=f2bf(v.w);
    ((u16x4*)out)[i] = u;
  }
}

extern "C" void kernel_launch(void* const* d_in, const int* in_sizes, int n_in,
                              void* d_out, int out_size, void* d_ws, size_t ws_size,
                              hipStream_t stream) {
  const float* x      = (const float*)d_in[0];
  const float* attsig = (const float*)d_in[1];
  const float* wq     = (const float*)d_in[2];
  const float* wk     = (const float*)d_in[3];
  const float* wv     = (const float*)d_in[4];
  const float* wo     = (const float*)d_in[5];
  const float* ln1w   = (const float*)d_in[6];
  const float* ln1b   = (const float*)d_in[7];
  const float* w1     = (const float*)d_in[8];
  const float* w2     = (const float*)d_in[9];
  const float* ln2w   = (const float*)d_in[10];
  const float* ln2b   = (const float*)d_in[11];

  char* ws = (char*)d_ws;
  unsigned short* xb    = (unsigned short*)(ws);              // 30720x1024 bf16
  unsigned short* wqkvb = (unsigned short*)(ws + 62914560ull);// 3072x1024
  unsigned short* wob   = (unsigned short*)(ws + 69206016ull);// 1024x1024
  unsigned short* w1b   = (unsigned short*)(ws + 71303168ull);// 2048x1024
  unsigned short* w2b   = (unsigned short*)(ws + 75497472ull);// 1024x2048
  unsigned short* qkv   = (unsigned short*)(ws + 79691776ull);// 30720x3072
  unsigned short* h1    = (unsigned short*)(ws + 268435456ull);// 30720x2048
  float*          lpart = (float*)(ws + 394264576ull);        // 8192

  float* outf = (float*)d_out;
  float* loss = outf + (size_t)M_TOK*DM;

  cast_bf16<<<2048,256,0,stream>>>(x,  xb,               M_TOK*DM/4);
  cast_bf16<<<256, 256,0,stream>>>(wq, wqkvb,            DM*DM/4);
  cast_bf16<<<256, 256,0,stream>>>(wk, wqkvb + DM*DM,    DM*DM/4);
  cast_bf16<<<256, 256,0,stream>>>(wv, wqkvb + 2*DM*DM,  DM*DM/4);
  cast_bf16<<<256, 256,0,stream>>>(wo, wob,              DM*DM/4);
  cast_bf16<<<512, 256,0,stream>>>(w1, w1b,              DM*DFF/4);
  cast_bf16<<<512, 256,0,stream>>>(w2, w2b,              DM*DFF/4);

  // QKV: [30720,1024] @ [3072,1024]^T -> bf16 [30720,3072]
  gemm256<0><<<NTM*(NQKV/256), 512, 0, stream>>>(xb, DM, wqkvb, DM, qkv, NQKV, nullptr, DM);

  attn_kernel<<<BBATCH*NH, 256, 0, stream>>>(qkv, attsig, lpart);
  reduce_loss<<<1,256,0,stream>>>(lpart, loss);

  // out_pre = ctx @ wo^T + x
  gemm256<1><<<NTM*(DM/256), 512, 0, stream>>>(qkv, NQKV, wob, DM, outf, DM, x, DM);
  ln_kernel<1><<<M_TOK,256,0,stream>>>(outf, ln1w, ln1b, xb);
  // h1 = relu(out @ w1^T)
  gemm256<2><<<NTM*(DFF/256), 512, 0, stream>>>(xb, DM, w1b, DM, h1, DFF, nullptr, DM);
  // ff_pre = h1 @ w2^T + out
  gemm256<1><<<NTM*(DM/256), 512, 0, stream>>>(h1, DFF, w2b, DFF, outf, DM, outf, DFF);
  ln_kernel<0><<<M_TOK,256,0,stream>>>(outf, ln2w, ln2b, nullptr);
}

// Round 4
// 760.102 us; speedup vs baseline: 1.3855x; 1.0535x over previous
//
#include <hip/hip_runtime.h>
#include <hip/hip_bf16.h>
#include <cstdint>

#define DM   1024
#define DFF  2048
#define NH   16
#define DK   64
#define BBATCH 512
#define LSEQ 60
#define M_TOK (BBATCH*LSEQ)   // 30720
#define NQKV (3*DM)           // 3072
#define NTM  120              // M_TOK / 256

typedef __attribute__((ext_vector_type(8))) short bf16x8;
typedef __attribute__((ext_vector_type(4))) float f32x4;
typedef __attribute__((ext_vector_type(8))) unsigned short u16x8;
typedef __attribute__((ext_vector_type(4))) unsigned short u16x4;

__device__ __forceinline__ unsigned short f2bf(float f) {
  union { float f; unsigned u; } x; x.f = f;
  unsigned r = x.u + 0x7fffu + ((x.u >> 16) & 1u);   // RNE
  return (unsigned short)(r >> 16);
}

__device__ __forceinline__ void gload_lds16(const void* g, void* l) {
  __builtin_amdgcn_global_load_lds(
      (const __attribute__((address_space(1))) unsigned int*)g,
      (__attribute__((address_space(3))) unsigned int*)l, 16, 0, 0);
}

template<int MO,int NO>
__device__ __forceinline__ void mf8(f32x4 (&acc)[8][4], const bf16x8 (&a)[4][2],
                                    const bf16x8 (&b)[2][2]) {
#pragma unroll
  for (int m=0;m<4;++m)
#pragma unroll
    for (int n=0;n<2;++n)
#pragma unroll
      for (int ks=0;ks<2;++ks)
        acc[MO+m][NO+n] = __builtin_amdgcn_mfma_f32_16x16x32_bf16(a[m][ks], b[n][ks], acc[MO+m][NO+n], 0,0,0);
}

// LDS short-offsets of the 4 32KB buffers (each holds a full 256x64 tile,
// rows 0..255 contiguous at 128B/row, st-swizzled byte ^= (row&7)<<4)
#define A0S 0
#define A1S 16384
#define B0S 32768
#define B1S 49152

// C = A(bf16,[M x K] lda) @ B(bf16,[N x K] ldb)^T ; 256x256 tile, BK=64,
// 8 waves (2Mx4N), 2-K-tile-unrolled 8-phase counted-vmcnt schedule
// (T1+T2+T3+T4+T5, all LDS offsets compile-time). nkt must be even, >=4.
// MODE 0: C bf16    MODE 1: C fp32 = acc + Res    MODE 2: C bf16 = relu(acc)
template<int MODE>
__global__ __launch_bounds__(512, 2)
void gemm256(const unsigned short* __restrict__ A, int lda,
             const unsigned short* __restrict__ B, int ldb,
             void* __restrict__ Cv, int ldc,
             const float* __restrict__ Res, int K) {
  __shared__ unsigned short sm[65536];
  const int t  = threadIdx.x;
  const int l  = t & 63, w = t >> 6;
  const int lo = l & 15, hi = l >> 4;
  const int wr = w >> 2, wc = w & 3;
  const int swz = (lo & 7) << 4;

  const int nwg = (int)gridDim.x;
  int wg = (int)blockIdx.x;
  wg = (wg & 7) * (nwg >> 3) + (wg >> 3);
  const int ng  = wg / (NTM*4);
  const int rem = wg - ng*(NTM*4);
  const long row0 = (long)(rem >> 2) * 256;
  const long col0 = (long)(ng*4 + (rem & 3)) * 256;

  // per-thread stage-slot geometry: slot j=0 row, shared col (shorts)
  const int srow = w*16 + (l>>3);
  const int scol = ((l & 7) ^ (l >> 3)) * 8;
  const unsigned short* pa = A + (size_t)(row0 + srow)*lda + scol;
  const unsigned short* pb = B + (size_t)(col0 + srow)*ldb + scol;
  const size_t ldaj = (size_t)8*lda,  ldah = (size_t)128*lda;
  const size_t ldbj = (size_t)8*ldb,  ldbh = (size_t)128*ldb;
  const int dls = (w*2)*512;   // LDS short-offset of this wave's slot-0 chunk

#define STAGE_A(bufS, h, kt) do { \
    const unsigned short* _s = pa + (size_t)(h)*ldah + (size_t)(kt)*64; \
    gload_lds16(_s,        &sm[(bufS) + (h)*8192 + dls]); \
    gload_lds16(_s + ldaj, &sm[(bufS) + (h)*8192 + dls + 512]); \
  } while(0)
#define STAGE_B(bufS, h, kt) do { \
    const unsigned short* _s = pb + (size_t)(h)*ldbh + (size_t)(kt)*64; \
    gload_lds16(_s,        &sm[(bufS) + (h)*8192 + dls]); \
    gload_lds16(_s + ldbj, &sm[(bufS) + (h)*8192 + dls + 512]); \
  } while(0)
#define LDA8(dst, bufS, mbase) do { \
  _Pragma("unroll") for (int m=0;m<4;++m) \
  _Pragma("unroll") for (int ks=0;ks<2;++ks) \
    dst[m][ks] = *(const bf16x8*)((const char*)sm + (bufS)*2 + \
        (wr*128 + ((mbase)+m)*16 + lo)*128 + ((ks*64 + hi*16) ^ swz)); \
  } while(0)
#define LDB4(dst, bufS, nbase) do { \
  _Pragma("unroll") for (int n=0;n<2;++n) \
  _Pragma("unroll") for (int ks=0;ks<2;++ks) \
    dst[n][ks] = *(const bf16x8*)((const char*)sm + (bufS)*2 + \
        (wc*64 + ((nbase)+n)*16 + lo)*128 + ((ks*64 + hi*16) ^ swz)); \
  } while(0)
#define BAR __builtin_amdgcn_s_barrier()
#define LG0 asm volatile("s_waitcnt lgkmcnt(0)" ::: "memory")
#define LG8 asm volatile("s_waitcnt lgkmcnt(8)" ::: "memory")
#define P1S __builtin_amdgcn_s_setprio(1)
#define P0S __builtin_amdgcn_s_setprio(0)

  f32x4 acc[8][4];
#pragma unroll
  for (int m=0;m<8;++m)
#pragma unroll
    for (int n=0;n<4;++n) acc[m][n] = (f32x4){0.f,0.f,0.f,0.f};

  const int nkt = K >> 6;

  // prologue: tiles 0 -> A0/B0, 1 -> A1/B1
  STAGE_A(A0S, 0, 0); STAGE_A(A0S, 1, 0);
  STAGE_B(B0S, 0, 0); STAGE_B(B0S, 1, 0);
  STAGE_A(A1S, 0, 1); STAGE_A(A1S, 1, 1);
  STAGE_B(B1S, 0, 1); STAGE_B(B1S, 1, 1);
  asm volatile("s_waitcnt vmcnt(8)" ::: "memory");
  BAR;

  for (int kt = 0; kt + 2 < nkt; kt += 2) {
    bf16x8 a[4][2], b0[2][2], b2[2][2];
    // ---- P1 (tile kt, A0/B0, quad 0,0) ----
    LDA8(a, A0S, 0); LDB4(b0, B0S, 0);
    LG8; BAR; LG0;
    P1S; mf8<0,0>(acc, a, b0); P0S; BAR;
    // ---- P2 (quad 0,2) ----
    LDB4(b2, B0S, 2);
    BAR; LG0;
    P1S; mf8<0,2>(acc, a, b2); P0S; BAR;
    // ---- P3 (quad 4,0) ----
    LDA8(a, A0S, 4);
    STAGE_B(B0S, 0, kt+2);
    BAR; LG0;
    P1S; mf8<4,0>(acc, a, b0); P0S; BAR;
    // ---- P4 (quad 4,2) ----
    STAGE_B(B0S, 1, kt+2);
    asm volatile("s_waitcnt vmcnt(4)" ::: "memory");
    BAR;
    P1S; mf8<4,2>(acc, a, b2); P0S; BAR;
    // ---- P5 (tile kt+1, A1/B1, quad 0,0) ----
    LDA8(a, A1S, 0); LDB4(b0, B1S, 0);
    STAGE_A(A0S, 0, kt+2);
    LG8; BAR; LG0;
    P1S; mf8<0,0>(acc, a, b0); P0S; BAR;
    // ---- P6 (quad 0,2) ----
    LDB4(b2, B1S, 2);
    STAGE_A(A0S, 1, kt+2);
    BAR; LG0;
    P1S; mf8<0,2>(acc, a, b2); P0S; BAR;
    // ---- P7 (quad 4,0) ----
    LDA8(a, A1S, 4);
    STAGE_B(B1S, 0, kt+3); STAGE_B(B1S, 1, kt+3);
    BAR; LG0;
    P1S; mf8<4,0>(acc, a, b0); P0S; BAR;
    // ---- P8 (quad 4,2) ----
    STAGE_A(A1S, 0, kt+3); STAGE_A(A1S, 1, kt+3);
    asm volatile("s_waitcnt vmcnt(8)" ::: "memory");
    BAR;
    P1S; mf8<4,2>(acc, a, b2); P0S; BAR;
  }

  // peeled last two tiles (no staging)
  {
    bf16x8 a[4][2], b0[2][2], b2[2][2];
    LDA8(a, A0S, 0); LDB4(b0, B0S, 0);
    LG8; BAR; LG0; P1S; mf8<0,0>(acc, a, b0); P0S; BAR;
    LDB4(b2, B0S, 2);
    BAR; LG0; P1S; mf8<0,2>(acc, a, b2); P0S; BAR;
    LDA8(a, A0S, 4);
    BAR; LG0; P1S; mf8<4,0>(acc, a, b0); P0S; BAR;
    asm volatile("s_waitcnt vmcnt(0)" ::: "memory");
    BAR; P1S; mf8<4,2>(acc, a, b2); P0S; BAR;
    LDA8(a, A1S, 0); LDB4(b0, B1S, 0);
    LG8; BAR; LG0; P1S; mf8<0,0>(acc, a, b0); P0S; BAR;
    LDB4(b2, B1S, 2);
    BAR; LG0; P1S; mf8<0,2>(acc, a, b2); P0S; BAR;
    LDA8(a, A1S, 4);
    BAR; LG0; P1S; mf8<4,0>(acc, a, b0); P0S; BAR;
    P1S; mf8<4,2>(acc, a, b2); P0S;
  }

  // epilogue
#pragma unroll
  for (int m=0;m<8;++m) {
#pragma unroll
    for (int r=0;r<4;++r) {
      const long row = row0 + wr*128 + m*16 + hi*4 + r;
      const size_t base = (size_t)row * ldc;
#pragma unroll
      for (int n=0;n<4;++n) {
        const long col = col0 + wc*64 + n*16 + lo;
        const float v = acc[m][n][r];
        if (MODE == 0) {
          ((unsigned short*)Cv)[base + col] = f2bf(v);
        } else if (MODE == 1) {
          ((float*)Cv)[base + col] = v + Res[base + col];
        } else {
          ((unsigned short*)Cv)[base + col] = f2bf(v > 0.f ? v : 0.f);
        }
      }
    }
  }
#undef STAGE_A
#undef STAGE_B
#undef LDA8
#undef LDB4
#undef BAR
#undef LG0
#undef LG8
#undef P1S
#undef P0S
}

// One block per (b,h). qkv: [M_TOK][3072] bf16 (Q|K|V). ctx written in-place over Q cols.
__global__ __launch_bounds__(256)
void attn_kernel(unsigned short* qkv, const float* __restrict__ att_sig,
                 float* __restrict__ loss_part) {
  __shared__ unsigned short qs[64*64], ks[64*64], vts[64*64], as2[64*64];
  __shared__ float red[4];
  const int bid = blockIdx.x;
  const int b = bid >> 4, h = bid & 15;
  const int t = threadIdx.x;
  const int l = t & 63, w = t >> 6, lo = l & 15, hi = l >> 4;

#pragma unroll
  for (int p=0;p<2;++p) {
    int row = p*32 + (t>>3);
    int d0  = (t&7)*8;
    u16x8 zq = {0,0,0,0,0,0,0,0}; u16x8 zk = zq; u16x8 zv = zq;
    if (row < LSEQ) {
      size_t g = (size_t)(b*LSEQ + row)*NQKV + h*DK + d0;
      zq = *(const u16x8*)(qkv + g);
      zk = *(const u16x8*)(qkv + g + DM);
      zv = *(const u16x8*)(qkv + g + 2*DM);
    }
    *(u16x8*)&qs[row*64 + d0] = zq;
    *(u16x8*)&ks[row*64 + d0] = zk;
#pragma unroll
    for (int j=0;j<8;++j) vts[(d0+j)*64 + row] = zv[j];
  }
  __syncthreads();

  f32x4 zero4 = {0.f,0.f,0.f,0.f};
  f32x4 sacc[4];
#pragma unroll
  for (int ct=0;ct<4;++ct) sacc[ct] = zero4;
  bf16x8 aq[2];
  aq[0] = *(const bf16x8*)&qs[(w*16+lo)*64 + hi*8];
  aq[1] = *(const bf16x8*)&qs[(w*16+lo)*64 + 32 + hi*8];
#pragma unroll
  for (int ct=0;ct<4;++ct)
#pragma unroll
    for (int kk=0;kk<2;++kk) {
      bf16x8 bk = *(const bf16x8*)&ks[(ct*16+lo)*64 + kk*32 + hi*8];
      sacc[ct] = __builtin_amdgcn_mfma_f32_16x16x32_bf16(aq[kk], bk, sacc[ct], 0,0,0);
    }

  float lloss = 0.f;
  const float SC = 0.125f;
#pragma unroll
  for (int r=0;r<4;++r) {
    int row = w*16 + hi*4 + r;
    float v0 = sacc[0][r]*SC, v1 = sacc[1][r]*SC, v2 = sacc[2][r]*SC;
    float v3 = (lo < 12) ? sacc[3][r]*SC : -__builtin_inff();
    float mx = fmaxf(fmaxf(v0,v1), fmaxf(v2,v3));
#pragma unroll
    for (int d=1; d<16; d<<=1) mx = fmaxf(mx, __shfl_xor(mx, d, 64));
    float p0=__expf(v0-mx), p1=__expf(v1-mx), p2=__expf(v2-mx), p3=__expf(v3-mx);
    float sm = p0+p1+p2+p3;
#pragma unroll
    for (int d=1; d<16; d<<=1) sm += __shfl_xor(sm, d, 64);
    float inv = 1.0f / sm;
    float a0=p0*inv, a1=p1*inv, a2=p2*inv, a3=p3*inv;
    if (row < LSEQ) {
      float df;
      df = a0 - att_sig[row*LSEQ + lo];       lloss += df*df;
      df = a1 - att_sig[row*LSEQ + 16 + lo];  lloss += df*df;
      df = a2 - att_sig[row*LSEQ + 32 + lo];  lloss += df*df;
      if (lo < 12) { df = a3 - att_sig[row*LSEQ + 48 + lo]; lloss += df*df; }
    }
    as2[row*64 + lo]      = f2bf(a0);
    as2[row*64 + 16 + lo] = f2bf(a1);
    as2[row*64 + 32 + lo] = f2bf(a2);
    as2[row*64 + 48 + lo] = f2bf(a3);
  }
  __syncthreads();

  f32x4 cacc[4];
#pragma unroll
  for (int n=0;n<4;++n) cacc[n] = zero4;
  bf16x8 ap[2];
  ap[0] = *(const bf16x8*)&as2[(w*16+lo)*64 + hi*8];
  ap[1] = *(const bf16x8*)&as2[(w*16+lo)*64 + 32 + hi*8];
#pragma unroll
  for (int n=0;n<4;++n)
#pragma unroll
    for (int kk=0;kk<2;++kk) {
      bf16x8 bv = *(const bf16x8*)&vts[(n*16+lo)*64 + kk*32 + hi*8];
      cacc[n] = __builtin_amdgcn_mfma_f32_16x16x32_bf16(ap[kk], bv, cacc[n], 0,0,0);
    }
#pragma unroll
  for (int r=0;r<4;++r) {
    int row = w*16 + hi*4 + r;
    if (row < LSEQ) {
      size_t g = (size_t)(b*LSEQ + row)*NQKV + h*DK;
#pragma unroll
      for (int n=0;n<4;++n)
        qkv[g + n*16 + lo] = f2bf(cacc[n][r]);
    }
  }

#pragma unroll
  for (int d=1; d<64; d<<=1) lloss += __shfl_xor(lloss, d, 64);
  if (l == 0) red[w] = lloss;
  __syncthreads();
  if (t == 0) loss_part[bid] = red[0]+red[1]+red[2]+red[3];
}

__global__ __launch_bounds__(256)
void reduce_loss(const float* __restrict__ part, float* __restrict__ out) {
  __shared__ float red[4];
  float s = 0.f;
  for (int i = threadIdx.x; i < BBATCH*NH; i += 256) s += part[i];
#pragma unroll
  for (int d=1; d<64; d<<=1) s += __shfl_xor(s, d, 64);
  if ((threadIdx.x & 63) == 0) red[threadIdx.x >> 6] = s;
  __syncthreads();
  if (threadIdx.x == 0) out[0] = red[0]+red[1]+red[2]+red[3];
}

template<int WB>
__global__ __launch_bounds__(256)
void ln_kernel(float* __restrict__ io, const float* __restrict__ gw,
               const float* __restrict__ gb, unsigned short* __restrict__ ob) {
  __shared__ float red[4];
  const int t = threadIdx.x;
  const size_t base = (size_t)blockIdx.x * DM;
  float4 v = ((const float4*)(io + base))[t];
  float s = v.x+v.y+v.z+v.w;
#pragma unroll
  for (int d=1; d<64; d<<=1) s += __shfl_xor(s, d, 64);
  if ((t&63)==0) red[t>>6] = s;
  __syncthreads();
  float mean = (red[0]+red[1]+red[2]+red[3]) * (1.f/DM);
  __syncthreads();
  float dx0=v.x-mean, dx1=v.y-mean, dx2=v.z-mean, dx3=v.w-mean;
  float q = dx0*dx0+dx1*dx1+dx2*dx2+dx3*dx3;
#pragma unroll
  for (int d=1; d<64; d<<=1) q += __shfl_xor(q, d, 64);
  if ((t&63)==0) red[t>>6] = q;
  __syncthreads();
  float var = (red[0]+red[1]+red[2]+red[3]) * (1.f/DM);
  float inv = rsqrtf(var + 1e-5f);
  float4 wv = ((const float4*)gw)[t];
  float4 bv = ((const float4*)gb)[t];
  float4 o;
  o.x = dx0*inv*wv.x + bv.x;
  o.y = dx1*inv*wv.y + bv.y;
  o.z = dx2*inv*wv.z + bv.z;
  o.w = dx3*inv*wv.w + bv.w;
  ((float4*)(io + base))[t] = o;
  if (WB) {
    u16x4 ub; ub[0]=f2bf(o.x); ub[1]=f2bf(o.y); ub[2]=f2bf(o.z); ub[3]=f2bf(o.w);
    *(u16x4*)(ob + base + t*4) = ub;
  }
}

// single fused cast dispatch: 9728 blocks, 1024 float4 per block
// block ranges: x[0,7680) wq[7680,7936) wk[7936,8192) wv[8192,8448)
//               wo[8448,8704) w1[8704,9216) w2[9216,9728)
__global__ __launch_bounds__(256)
void cast_all(const float* __restrict__ x,  const float* __restrict__ wq,
              const float* __restrict__ wk, const float* __restrict__ wv,
              const float* __restrict__ wo, const float* __restrict__ w1,
              const float* __restrict__ w2,
              unsigned short* __restrict__ xb, unsigned short* __restrict__ wqkvb,
              unsigned short* __restrict__ wob, unsigned short* __restrict__ w1b,
              unsigned short* __restrict__ w2b) {
  const int b = blockIdx.x;
  const float* src; unsigned short* dst; int off;
  if (b < 7680)      { src = x;  dst = xb;              off = b; }
  else if (b < 7936) { src = wq; dst = wqkvb;           off = b - 7680; }
  else if (b < 8192) { src = wk; dst = wqkvb + 1048576; off = b - 7936; }
  else if (b < 8448) { src = wv; dst = wqkvb + 2097152; off = b - 8192; }
  else if (b < 8704) { src = wo; dst = wob;             off = b - 8448; }
  else if (b < 9216) { src = w1; dst = w1b;             off = b - 8704; }
  else               { src = w2; dst = w2b;             off = b - 9216; }
  int i = off*1024 + threadIdx.x;
#pragma unroll
  for (int u=0; u<4; ++u, i += 256) {
    float4 v = ((const float4*)src)[i];
    u16x4 p; p[0]=f2bf(v.x); p[1]=f2bf(v.y); p[2]=f2bf(v.z); p[3]=f2bf(v.w);
    ((u16x4*)dst)[i] = p;
  }
}

extern "C" void kernel_launch(void* const* d_in, const int* in_sizes, int n_in,
                              void* d_out, int out_size, void* d_ws, size_t ws_size,
                              hipStream_t stream) {
  const float* x      = (const float*)d_in[0];
  const float* attsig = (const float*)d_in[1];
  const float* wq     = (const float*)d_in[2];
  const float* wk     = (const float*)d_in[3];
  const float* wv     = (const float*)d_in[4];
  const float* wo     = (const float*)d_in[5];
  const float* ln1w   = (const float*)d_in[6];
  const float* ln1b   = (const float*)d_in[7];
  const float* w1     = (const float*)d_in[8];
  const float* w2     = (const float*)d_in[9];
  const float* ln2w   = (const float*)d_in[10];
  const float* ln2b   = (const float*)d_in[11];

  char* ws = (char*)d_ws;
  unsigned short* xb    = (unsigned short*)(ws);              // 30720x1024 bf16
  unsigned short* wqkvb = (unsigned short*)(ws + 62914560ull);// 3072x1024
  unsigned short* wob   = (unsigned short*)(ws + 69206016ull);// 1024x1024
  unsigned short* w1b   = (unsigned short*)(ws + 71303168ull);// 2048x1024
  unsigned short* w2b   = (unsigned short*)(ws + 75497472ull);// 1024x2048
  unsigned short* qkv   = (unsigned short*)(ws + 79691776ull);// 30720x3072
  unsigned short* h1    = (unsigned short*)(ws + 268435456ull);// 30720x2048
  float*          lpart = (float*)(ws + 394264576ull);        // 8192

  float* outf = (float*)d_out;
  float* loss = outf + (size_t)M_TOK*DM;

  cast_all<<<9728,256,0,stream>>>(x, wq, wk, wv, wo, w1, w2,
                                  xb, wqkvb, wob, w1b, w2b);

  // QKV: [30720,1024] @ [3072,1024]^T -> bf16 [30720,3072]
  gemm256<0><<<NTM*(NQKV/256), 512, 0, stream>>>(xb, DM, wqkvb, DM, qkv, NQKV, nullptr, DM);

  attn_kernel<<<BBATCH*NH, 256, 0, stream>>>(qkv, attsig, lpart);
  reduce_loss<<<1,256,0,stream>>>(lpart, loss);

  // out_pre = ctx @ wo^T + x
  gemm256<1><<<NTM*(DM/256), 512, 0, stream>>>(qkv, NQKV, wob, DM, outf, DM, x, DM);
  ln_kernel<1><<<M_TOK,256,0,stream>>>(outf, ln1w, ln1b, xb);
  // h1 = relu(out @ w1^T)
  gemm256<2><<<NTM*(DFF/256), 512, 0, stream>>>(xb, DM, w1b, DM, h1, DFF, nullptr, DM);
  // ff_pre = h1 @ w2^T + out
  gemm256<1><<<NTM*(DM/256), 512, 0, stream>>>(h1, DFF, w2b, DFF, outf, DM, outf, DFF);
  ln_kernel<0><<<M_TOK,256,0,stream>>>(outf, ln2w, ln2b, nullptr);
}